// Round 5
// baseline (418.251 us; speedup 1.0000x reference)
//
#include <hip/hip_runtime.h>

static constexpr int NN = 100000;   // nodes
static constexpr int NE = 500000;   // edges
static constexpr int D  = 32;       // channels
static constexpr int NR = 16;       // relations
static constexpr int HB = 256;      // histogram / scatter blocks
static constexpr int ES = (NE + HB - 1) / HB;   // edges per hist/scatter block
static constexpr int CH = 256;      // edges per (type,chunk) pass in k_edge
static constexpr int NY = 128;      // chunk blocks per type

// ---------------- K1: h = x @ W  (+ fused block-local edge-type histogram)
__global__ __launch_bounds__(256) void k_xw_hist(const float* __restrict__ x,
                                                 const float* __restrict__ W,
                                                 const int* __restrict__ et,
                                                 float* __restrict__ h,
                                                 int* __restrict__ cnt) {
    __shared__ float sW[D * D];
    __shared__ int lh[NR];
    if (threadIdx.x < NR) lh[threadIdx.x] = 0;
    for (int i = threadIdx.x; i < D * D; i += 256) sW[i] = W[i];
    __syncthreads();

    if (blockIdx.x < HB) {   // 256 blocks histogram -> 4096 global atomics
        const int beg = blockIdx.x * ES, end = min(beg + ES, NE);
        for (int e = beg + (int)threadIdx.x; e < end; e += 256)
            atomicAdd(&lh[et[e]], 1);
    }

    const int n = blockIdx.x * 256 + threadIdx.x;
    if (n < NN) {
        float xr[D];
        const float4* xv = reinterpret_cast<const float4*>(x + (size_t)n * D);
        #pragma unroll
        for (int k = 0; k < 8; ++k) {
            float4 v = xv[k];
            xr[4*k+0] = v.x; xr[4*k+1] = v.y; xr[4*k+2] = v.z; xr[4*k+3] = v.w;
        }
        float4* hv = reinterpret_cast<float4*>(h + (size_t)n * D);
        #pragma unroll
        for (int oc = 0; oc < 8; ++oc) {
            float a0 = 0.f, a1 = 0.f, a2 = 0.f, a3 = 0.f;
            #pragma unroll
            for (int i = 0; i < D; ++i) {
                float xi = xr[i];
                a0 += xi * sW[i*D + 4*oc + 0];
                a1 += xi * sW[i*D + 4*oc + 1];
                a2 += xi * sW[i*D + 4*oc + 2];
                a3 += xi * sW[i*D + 4*oc + 3];
            }
            hv[oc] = make_float4(a0, a1, a2, a3);
        }
    }
    __syncthreads();
    if (blockIdx.x < HB && threadIdx.x < NR && lh[threadIdx.x] > 0)
        atomicAdd(&cnt[threadIdx.x], lh[threadIdx.x]);
}

// ---------------- K1b: bin offsets + scatter cursors --------------------
__global__ void k_prep(const int* __restrict__ cnt,
                       int* __restrict__ off,
                       int* __restrict__ cursor) {
    if (threadIdx.x == 0) {
        int s = 0;
        for (int t = 0; t < NR; ++t) { off[t] = s; cursor[t] = s; s += cnt[t]; }
        off[NR] = s;
    }
}

// ---------------- K2a: scatter into type buckets (range-grab) -----------
__global__ __launch_bounds__(256) void k_scatter(const int* __restrict__ ei,
                                                 const int* __restrict__ et,
                                                 int* __restrict__ cursor,
                                                 int2* __restrict__ rec) {
    __shared__ int lh[NR], lcur[NR];
    if (threadIdx.x < NR) lh[threadIdx.x] = 0;
    __syncthreads();
    const int beg = blockIdx.x * ES, end = min(beg + ES, NE);
    for (int e = beg + (int)threadIdx.x; e < end; e += 256)
        atomicAdd(&lh[et[e]], 1);
    __syncthreads();
    if (threadIdx.x < NR)
        lcur[threadIdx.x] = (lh[threadIdx.x] > 0)
                          ? atomicAdd(&cursor[threadIdx.x], lh[threadIdx.x]) : 0;
    __syncthreads();
    for (int e = beg + (int)threadIdx.x; e < end; e += 256) {
        const int t = et[e];
        const int pos = atomicAdd(&lcur[t], 1);
        rec[pos] = make_int2(ei[e], ei[NE + e]);
    }
}

// ---------------- K2b: per-edge matvec + scatter-add (type-specialized) -
// blockIdx.x = type, blockIdx.y = chunk. R column in registers (lane o
// holds R[:,o]); 4 edges in flight per half-wave; h rows broadcast via a
// 4 KB LDS buffer read as float4 (ds_read_b128, conflict-free broadcast).
__global__ __launch_bounds__(256, 8) void k_edge(const float* __restrict__ h,
                                                 const int2* __restrict__ rec,
                                                 const int* __restrict__ off,
                                                 const float* __restrict__ rel,
                                                 float* __restrict__ acc) {
    const int t = blockIdx.x;
    __shared__ float sh[8][4][D];
    const int o = threadIdx.x & 31;        // output channel
    const int g = threadIdx.x >> 5;        // half-wave group 0..7
    float Rc[32];
    const float* Rt = rel + t * 1024;
    #pragma unroll
    for (int i = 0; i < 32; ++i) Rc[i] = Rt[i * 32 + o];

    const int beg = off[t], end = off[t + 1];
    for (int start = beg + blockIdx.y * CH; start < end; start += NY * CH) {
        const int stop = min(start + CH, end);
        for (int e0 = start + g * 4; e0 < stop; e0 += 32) {
            int2 r[4];
            #pragma unroll
            for (int j = 0; j < 4; ++j)
                r[j] = rec[min(e0 + j, stop - 1)];
            float hv[4];
            #pragma unroll
            for (int j = 0; j < 4; ++j)
                hv[j] = h[(size_t)r[j].x * D + o];
            #pragma unroll
            for (int j = 0; j < 4; ++j)
                sh[g][j][o] = hv[j];
            __asm__ volatile("s_waitcnt lgkmcnt(0)" ::: "memory");
            float a4[4] = {0.f, 0.f, 0.f, 0.f};
            #pragma unroll
            for (int j = 0; j < 4; ++j) {
                const float4* row = reinterpret_cast<const float4*>(sh[g][j]);
                #pragma unroll
                for (int q = 0; q < 8; ++q) {
                    const float4 v = row[q];
                    a4[j] = fmaf(v.x, Rc[4*q+0], a4[j]);
                    a4[j] = fmaf(v.y, Rc[4*q+1], a4[j]);
                    a4[j] = fmaf(v.z, Rc[4*q+2], a4[j]);
                    a4[j] = fmaf(v.w, Rc[4*q+3], a4[j]);
                }
            }
            #pragma unroll
            for (int j = 0; j < 4; ++j)
                if (e0 + j < stop)
                    atomicAdd(acc + (size_t)r[j].y * D + o, a4[j]);
            __asm__ volatile("" ::: "memory");
        }
    }
}

// ---------------- K3a: scores + per-block online (max, sum-exp) ---------
__global__ __launch_bounds__(256) void k_score(const float* __restrict__ acc,
                                               const float* __restrict__ att,
                                               float* __restrict__ scores,
                                               float* __restrict__ pmax,
                                               float* __restrict__ psum) {
    __shared__ float sA[D];
    __shared__ float shm[4], shs[4];
    if (threadIdx.x < D) sA[threadIdx.x] = att[threadIdx.x];
    __syncthreads();
    const int n = blockIdx.x * 256 + threadIdx.x;
    float s = -3.4e38f;
    if (n < NN) {
        const float4* av = reinterpret_cast<const float4*>(acc + (size_t)n * D);
        float v0 = 0.f;
        #pragma unroll
        for (int k = 0; k < 8; ++k) {
            float4 v = av[k];
            v0 += v.x * sA[4*k+0] + v.y * sA[4*k+1] + v.z * sA[4*k+2] + v.w * sA[4*k+3];
        }
        scores[n] = v0;
        s = v0;
    }
    float m = s;
    #pragma unroll
    for (int offt = 32; offt > 0; offt >>= 1)
        m = fmaxf(m, __shfl_down(m, offt, 64));
    if ((threadIdx.x & 63) == 0) shm[threadIdx.x >> 6] = m;
    __syncthreads();
    const float bm = fmaxf(fmaxf(shm[0], shm[1]), fmaxf(shm[2], shm[3]));
    float e = (n < NN) ? expf(s - bm) : 0.f;
    #pragma unroll
    for (int offt = 32; offt > 0; offt >>= 1)
        e += __shfl_down(e, offt, 64);
    if ((threadIdx.x & 63) == 0) shs[threadIdx.x >> 6] = e;
    __syncthreads();
    if (threadIdx.x == 0) {
        pmax[blockIdx.x] = bm;
        psum[blockIdx.x] = shs[0] + shs[1] + shs[2] + shs[3];
    }
}

// ---------------- K3b: fused combine + scale ----------------------------
__global__ __launch_bounds__(256) void k_final(float* __restrict__ out,
                                               const float* __restrict__ scores,
                                               const float* __restrict__ pmax,
                                               const float* __restrict__ psum,
                                               int nb) {
    __shared__ float shm[4], shs[4];
    const int tid = threadIdx.x;
    float m = -3.4e38f, s = 0.f;
    for (int i = tid; i < nb; i += 256) {
        const float mi = pmax[i], si = psum[i];
        const float M = fmaxf(m, mi);
        s = s * expf(m - M) + si * expf(mi - M);
        m = M;
    }
    #pragma unroll
    for (int offt = 32; offt > 0; offt >>= 1) {
        const float mo = __shfl_down(m, offt, 64);
        const float so = __shfl_down(s, offt, 64);
        const float M = fmaxf(m, mo);
        s = s * expf(m - M) + so * expf(mo - M);
        m = M;
    }
    if ((tid & 63) == 0) { shm[tid >> 6] = m; shs[tid >> 6] = s; }
    __syncthreads();
    float M = shm[0], S = shs[0];
    #pragma unroll
    for (int w = 1; w < 4; ++w) {
        const float Mn = fmaxf(M, shm[w]);
        S = S * expf(M - Mn) + shs[w] * expf(shm[w] - Mn);
        M = Mn;
    }
    const int idx = blockIdx.x * 256 + tid;        // float4 index, exact grid
    const int n = idx >> 3;
    const float w = expf(scores[n] - M) / S;
    float4* p = reinterpret_cast<float4*>(out);
    float4 v = p[idx];
    v.x = fmaxf(v.x * w, 0.f);
    v.y = fmaxf(v.y * w, 0.f);
    v.z = fmaxf(v.z * w, 0.f);
    v.w = fmaxf(v.w * w, 0.f);
    p[idx] = v;
}

extern "C" void kernel_launch(void* const* d_in, const int* in_sizes, int n_in,
                              void* d_out, int out_size, void* d_ws, size_t ws_size,
                              hipStream_t stream) {
    const float* x   = (const float*)d_in[0];
    const int*   ei  = (const int*)  d_in[1];
    const int*   et  = (const int*)  d_in[2];
    const float* W   = (const float*)d_in[3];
    const float* rel = (const float*)d_in[4];
    const float* att = (const float*)d_in[5];
    float* out = (float*)d_out;

    // ws layout: h[NN*D] | rec[NE int2] | cnt[16] | off[17] | cursor[16]
    //            | pmax[512] | psum[512];  scores overlays rec after k_edge
    float* h      = (float*)d_ws;
    int2*  rec    = (int2*)(h + (size_t)NN * D);
    int*   cnt    = (int*)(rec + NE);
    int*   off    = cnt + NR;
    int*   cursor = off + NR + 1;
    float* pmax   = (float*)(cursor + NR);
    float* psum   = pmax + 512;
    float* scores = (float*)rec;

    hipMemsetAsync(d_out, 0, (size_t)NN * D * sizeof(float), stream);
    hipMemsetAsync(cnt, 0, NR * sizeof(int), stream);

    const int nb_n = (NN + 255) / 256;           // 391
    k_xw_hist<<<nb_n, 256, 0, stream>>>(x, W, et, h, cnt);
    k_prep<<<1, 64, 0, stream>>>(cnt, off, cursor);
    k_scatter<<<HB, 256, 0, stream>>>(ei, et, cursor, rec);

    k_edge<<<dim3(NR, NY), 256, 0, stream>>>(h, rec, off, rel, out);

    k_score<<<nb_n, 256, 0, stream>>>(out, att, scores, pmax, psum);
    k_final<<<(NN * (D / 4)) / 256, 256, 0, stream>>>(out, scores, pmax, psum, nb_n);
}

// Round 6
// 116.709 us; speedup vs baseline: 3.5837x; 3.5837x over previous
//
#include <hip/hip_runtime.h>

static constexpr int NN = 100000;   // nodes
static constexpr int NE = 500000;   // edges
static constexpr int D  = 32;       // channels
static constexpr int NR = 16;       // relations
static constexpr int HB = 256;      // histogram / scatter blocks
static constexpr int ES = (NE + HB - 1) / HB;   // edges per hist/scatter block
static constexpr int CH = 256;      // edges per (type,chunk) pass in k_edge
static constexpr int NY = 128;      // chunk blocks per type

// ---------------- K1: h = x @ W  (+ fused block-local edge-type histogram)
__global__ __launch_bounds__(256) void k_xw_hist(const float* __restrict__ x,
                                                 const float* __restrict__ W,
                                                 const int* __restrict__ et,
                                                 float* __restrict__ h,
                                                 int* __restrict__ cnt) {
    __shared__ float sW[D * D];
    __shared__ int lh[NR];
    if (threadIdx.x < NR) lh[threadIdx.x] = 0;
    for (int i = threadIdx.x; i < D * D; i += 256) sW[i] = W[i];
    __syncthreads();

    if (blockIdx.x < HB) {   // 256 blocks histogram -> 4096 global atomics
        const int beg = blockIdx.x * ES, end = min(beg + ES, NE);
        for (int e = beg + (int)threadIdx.x; e < end; e += 256)
            atomicAdd(&lh[et[e]], 1);
    }

    const int n = blockIdx.x * 256 + threadIdx.x;
    if (n < NN) {
        float xr[D];
        const float4* xv = reinterpret_cast<const float4*>(x + (size_t)n * D);
        #pragma unroll
        for (int k = 0; k < 8; ++k) {
            float4 v = xv[k];
            xr[4*k+0] = v.x; xr[4*k+1] = v.y; xr[4*k+2] = v.z; xr[4*k+3] = v.w;
        }
        float4* hv = reinterpret_cast<float4*>(h + (size_t)n * D);
        #pragma unroll
        for (int oc = 0; oc < 8; ++oc) {
            float a0 = 0.f, a1 = 0.f, a2 = 0.f, a3 = 0.f;
            #pragma unroll
            for (int i = 0; i < D; ++i) {
                float xi = xr[i];
                a0 += xi * sW[i*D + 4*oc + 0];
                a1 += xi * sW[i*D + 4*oc + 1];
                a2 += xi * sW[i*D + 4*oc + 2];
                a3 += xi * sW[i*D + 4*oc + 3];
            }
            hv[oc] = make_float4(a0, a1, a2, a3);
        }
    }
    __syncthreads();
    if (blockIdx.x < HB && threadIdx.x < NR && lh[threadIdx.x] > 0)
        atomicAdd(&cnt[threadIdx.x], lh[threadIdx.x]);
}

// ---------------- K1b: bin offsets + scatter cursors --------------------
__global__ void k_prep(const int* __restrict__ cnt,
                       int* __restrict__ off,
                       int* __restrict__ cursor) {
    if (threadIdx.x == 0) {
        int s = 0;
        for (int t = 0; t < NR; ++t) { off[t] = s; cursor[t] = s; s += cnt[t]; }
        off[NR] = s;
    }
}

// ---------------- K2a: scatter into type buckets (range-grab) -----------
__global__ __launch_bounds__(256) void k_scatter(const int* __restrict__ ei,
                                                 const int* __restrict__ et,
                                                 int* __restrict__ cursor,
                                                 int2* __restrict__ rec) {
    __shared__ int lh[NR], lcur[NR];
    if (threadIdx.x < NR) lh[threadIdx.x] = 0;
    __syncthreads();
    const int beg = blockIdx.x * ES, end = min(beg + ES, NE);
    for (int e = beg + (int)threadIdx.x; e < end; e += 256)
        atomicAdd(&lh[et[e]], 1);
    __syncthreads();
    if (threadIdx.x < NR)
        lcur[threadIdx.x] = (lh[threadIdx.x] > 0)
                          ? atomicAdd(&cursor[threadIdx.x], lh[threadIdx.x]) : 0;
    __syncthreads();
    for (int e = beg + (int)threadIdx.x; e < end; e += 256) {
        const int t = et[e];
        const int pos = atomicAdd(&lcur[t], 1);
        rec[pos] = make_int2(ei[e], ei[NE + e]);
    }
}

// ---------------- K2b: per-edge matvec + scatter-add (type-specialized) -
// blockIdx.x = type, blockIdx.y = chunk. R column in registers (lane o
// holds R[:,o]); 4 edges in flight per half-wave; h rows broadcast via a
// 4 KB LDS buffer read as float4. NO launch-bounds min-wave arg: round-5's
// (256,8) capped VGPR at 32 -> Rc spilled to scratch -> 1.5 GB HBM traffic.
__global__ __launch_bounds__(256) void k_edge(const float* __restrict__ h,
                                              const int2* __restrict__ rec,
                                              const int* __restrict__ off,
                                              const float* __restrict__ rel,
                                              float* __restrict__ acc) {
    const int t = blockIdx.x;
    __shared__ float sh[8][4][D];
    const int o = threadIdx.x & 31;        // output channel
    const int g = threadIdx.x >> 5;        // half-wave group 0..7
    float Rc[32];
    const float* Rt = rel + t * 1024;
    #pragma unroll
    for (int i = 0; i < 32; ++i) Rc[i] = Rt[i * 32 + o];

    const int beg = off[t], end = off[t + 1];
    for (int start = beg + blockIdx.y * CH; start < end; start += NY * CH) {
        const int stop = min(start + CH, end);
        for (int e0 = start + g * 4; e0 < stop; e0 += 32) {
            int2 r[4];
            #pragma unroll
            for (int j = 0; j < 4; ++j)
                r[j] = rec[min(e0 + j, stop - 1)];
            float hv[4];
            #pragma unroll
            for (int j = 0; j < 4; ++j)
                hv[j] = h[(size_t)r[j].x * D + o];
            #pragma unroll
            for (int j = 0; j < 4; ++j)
                sh[g][j][o] = hv[j];
            __asm__ volatile("s_waitcnt lgkmcnt(0)" ::: "memory");
            float a4[4] = {0.f, 0.f, 0.f, 0.f};
            #pragma unroll
            for (int j = 0; j < 4; ++j) {
                const float4* row = reinterpret_cast<const float4*>(sh[g][j]);
                #pragma unroll
                for (int q = 0; q < 8; ++q) {
                    const float4 v = row[q];
                    a4[j] = fmaf(v.x, Rc[4*q+0], a4[j]);
                    a4[j] = fmaf(v.y, Rc[4*q+1], a4[j]);
                    a4[j] = fmaf(v.z, Rc[4*q+2], a4[j]);
                    a4[j] = fmaf(v.w, Rc[4*q+3], a4[j]);
                }
            }
            #pragma unroll
            for (int j = 0; j < 4; ++j)
                if (e0 + j < stop)
                    atomicAdd(acc + (size_t)r[j].y * D + o, a4[j]);
            __asm__ volatile("" ::: "memory");
        }
    }
}

// ---------------- K3a: scores + per-block online (max, sum-exp) ---------
__global__ __launch_bounds__(256) void k_score(const float* __restrict__ acc,
                                               const float* __restrict__ att,
                                               float* __restrict__ scores,
                                               float* __restrict__ pmax,
                                               float* __restrict__ psum) {
    __shared__ float sA[D];
    __shared__ float shm[4], shs[4];
    if (threadIdx.x < D) sA[threadIdx.x] = att[threadIdx.x];
    __syncthreads();
    const int n = blockIdx.x * 256 + threadIdx.x;
    float s = -3.4e38f;
    if (n < NN) {
        const float4* av = reinterpret_cast<const float4*>(acc + (size_t)n * D);
        float v0 = 0.f;
        #pragma unroll
        for (int k = 0; k < 8; ++k) {
            float4 v = av[k];
            v0 += v.x * sA[4*k+0] + v.y * sA[4*k+1] + v.z * sA[4*k+2] + v.w * sA[4*k+3];
        }
        scores[n] = v0;
        s = v0;
    }
    float m = s;
    #pragma unroll
    for (int offt = 32; offt > 0; offt >>= 1)
        m = fmaxf(m, __shfl_down(m, offt, 64));
    if ((threadIdx.x & 63) == 0) shm[threadIdx.x >> 6] = m;
    __syncthreads();
    const float bm = fmaxf(fmaxf(shm[0], shm[1]), fmaxf(shm[2], shm[3]));
    float e = (n < NN) ? expf(s - bm) : 0.f;
    #pragma unroll
    for (int offt = 32; offt > 0; offt >>= 1)
        e += __shfl_down(e, offt, 64);
    if ((threadIdx.x & 63) == 0) shs[threadIdx.x >> 6] = e;
    __syncthreads();
    if (threadIdx.x == 0) {
        pmax[blockIdx.x] = bm;
        psum[blockIdx.x] = shs[0] + shs[1] + shs[2] + shs[3];
    }
}

// ---------------- K3b: fused combine + scale ----------------------------
__global__ __launch_bounds__(256) void k_final(float* __restrict__ out,
                                               const float* __restrict__ scores,
                                               const float* __restrict__ pmax,
                                               const float* __restrict__ psum,
                                               int nb) {
    __shared__ float shm[4], shs[4];
    const int tid = threadIdx.x;
    float m = -3.4e38f, s = 0.f;
    for (int i = tid; i < nb; i += 256) {
        const float mi = pmax[i], si = psum[i];
        const float M = fmaxf(m, mi);
        s = s * expf(m - M) + si * expf(mi - M);
        m = M;
    }
    #pragma unroll
    for (int offt = 32; offt > 0; offt >>= 1) {
        const float mo = __shfl_down(m, offt, 64);
        const float so = __shfl_down(s, offt, 64);
        const float M = fmaxf(m, mo);
        s = s * expf(m - M) + so * expf(mo - M);
        m = M;
    }
    if ((tid & 63) == 0) { shm[tid >> 6] = m; shs[tid >> 6] = s; }
    __syncthreads();
    float M = shm[0], S = shs[0];
    #pragma unroll
    for (int w = 1; w < 4; ++w) {
        const float Mn = fmaxf(M, shm[w]);
        S = S * expf(M - Mn) + shs[w] * expf(shm[w] - Mn);
        M = Mn;
    }
    const int idx = blockIdx.x * 256 + tid;        // float4 index, exact grid
    const int n = idx >> 3;
    const float w = expf(scores[n] - M) / S;
    float4* p = reinterpret_cast<float4*>(out);
    float4 v = p[idx];
    v.x = fmaxf(v.x * w, 0.f);
    v.y = fmaxf(v.y * w, 0.f);
    v.z = fmaxf(v.z * w, 0.f);
    v.w = fmaxf(v.w * w, 0.f);
    p[idx] = v;
}

extern "C" void kernel_launch(void* const* d_in, const int* in_sizes, int n_in,
                              void* d_out, int out_size, void* d_ws, size_t ws_size,
                              hipStream_t stream) {
    const float* x   = (const float*)d_in[0];
    const int*   ei  = (const int*)  d_in[1];
    const int*   et  = (const int*)  d_in[2];
    const float* W   = (const float*)d_in[3];
    const float* rel = (const float*)d_in[4];
    const float* att = (const float*)d_in[5];
    float* out = (float*)d_out;

    // ws layout: h[NN*D] | rec[NE int2] | cnt[16] | off[17] | cursor[16]
    //            | pmax[512] | psum[512];  scores overlays rec after k_edge
    float* h      = (float*)d_ws;
    int2*  rec    = (int2*)(h + (size_t)NN * D);
    int*   cnt    = (int*)(rec + NE);
    int*   off    = cnt + NR;
    int*   cursor = off + NR + 1;
    float* pmax   = (float*)(cursor + NR);
    float* psum   = pmax + 512;
    float* scores = (float*)rec;

    hipMemsetAsync(d_out, 0, (size_t)NN * D * sizeof(float), stream);
    hipMemsetAsync(cnt, 0, NR * sizeof(int), stream);

    const int nb_n = (NN + 255) / 256;           // 391
    k_xw_hist<<<nb_n, 256, 0, stream>>>(x, W, et, h, cnt);
    k_prep<<<1, 64, 0, stream>>>(cnt, off, cursor);
    k_scatter<<<HB, 256, 0, stream>>>(ei, et, cursor, rec);

    k_edge<<<dim3(NR, NY), 256, 0, stream>>>(h, rec, off, rel, out);

    k_score<<<nb_n, 256, 0, stream>>>(out, att, scores, pmax, psum);
    k_final<<<(NN * (D / 4)) / 256, 256, 0, stream>>>(out, scores, pmax, psum, nb_n);
}